// Round 15
// baseline (430.878 us; speedup 1.0000x reference)
//
#include <hip/hip_runtime.h>
#include <stdint.h>

typedef short bf16x8 __attribute__((ext_vector_type(8)));
typedef float f32x4 __attribute__((ext_vector_type(4)));

#define M_ROWS 8192
#define N_OUT  4096
#define K_DIM  4096
#define NW     16777216.0   // number of weights

// ---------------- async global->LDS (16B per lane) ----------------
__device__ __forceinline__ void gload16(const void* g, void* l) {
    __builtin_amdgcn_global_load_lds((const __attribute__((address_space(1))) void*)g,
                                     (__attribute__((address_space(3))) void*)l,
                                     16, 0, 0);
}

// RNE f32 -> bf16 bits
__device__ __forceinline__ unsigned short f2bf(float f) {
    unsigned u = __float_as_uint(f);
    unsigned r = 0x7FFFu + ((u >> 16) & 1u);
    return (unsigned short)((u + r) >> 16);
}

// ------- fused: gamma partial-sum (W) + x f32->bf16 conversion -------
__global__ __launch_bounds__(256) void k_gamma_cvt(const float* __restrict__ w,
                                                   const float* __restrict__ x,
                                                   unsigned short* __restrict__ xb,
                                                   double* __restrict__ sum) {
    const int idx = blockIdx.x * blockDim.x + threadIdx.x;
    const int stride = gridDim.x * blockDim.x;

    const int wn4 = (K_DIM * N_OUT) / 4;
    const float4* w4 = (const float4*)w;
    double local = 0.0;
    for (int i = idx; i < wn4; i += stride) {
        float4 v = w4[i];
        local += (double)fabsf(v.x) + (double)fabsf(v.y) +
                 (double)fabsf(v.z) + (double)fabsf(v.w);
    }

    const int xn4 = (M_ROWS * K_DIM) / 4;
    const float4* x4 = (const float4*)x;
    for (int i = idx; i < xn4; i += stride) {
        float4 v = x4[i];
        uint2 pk;
        pk.x = (unsigned)f2bf(v.x) | ((unsigned)f2bf(v.y) << 16);
        pk.y = (unsigned)f2bf(v.z) | ((unsigned)f2bf(v.w) << 16);
        ((uint2*)xb)[i] = pk;
    }

    __shared__ double sm[256];
    sm[threadIdx.x] = local;
    __syncthreads();
    for (int s = 128; s > 0; s >>= 1) {
        if (threadIdx.x < s) sm[threadIdx.x] += sm[threadIdx.x + s];
        __syncthreads();
    }
    if (threadIdx.x == 0) atomicAdd(sum, sm[0]);
}

// ---------------- gamma only (fallback path) ----------------
__global__ __launch_bounds__(256) void k_gamma(const float* __restrict__ w,
                                               double* __restrict__ sum) {
    const int n4 = (K_DIM * N_OUT) / 4;
    int idx = blockIdx.x * blockDim.x + threadIdx.x;
    int stride = gridDim.x * blockDim.x;
    const float4* w4 = (const float4*)w;
    double local = 0.0;
    for (int i = idx; i < n4; i += stride) {
        float4 v = w4[i];
        local += (double)fabsf(v.x) + (double)fabsf(v.y) +
                 (double)fabsf(v.z) + (double)fabsf(v.w);
    }
    __shared__ double sm[256];
    sm[threadIdx.x] = local;
    __syncthreads();
    for (int s = 128; s > 0; s >>= 1) {
        if (threadIdx.x < s) sm[threadIdx.x] += sm[threadIdx.x + s];
        __syncthreads();
    }
    if (threadIdx.x == 0) atomicAdd(sum, sm[0]);
}

// ---------------- quantize W -> ternary bf16 + bin counts ----------------
__global__ __launch_bounds__(256) void k_quant(const float* __restrict__ w,
                                               const double* __restrict__ sum,
                                               unsigned short* __restrict__ wq,
                                               unsigned int* __restrict__ counts,
                                               int do_store) {
    const float gamma = (float)(*sum / NW);
    const float denom = gamma + 1e-8f;
    const int n4 = (K_DIM * N_OUT) / 4;
    int idx = blockIdx.x * blockDim.x + threadIdx.x;
    int stride = gridDim.x * blockDim.x;
    const float4* w4 = (const float4*)w;
    unsigned cm = 0, cp = 0;
    for (int i = idx; i < n4; i += stride) {
        float4 v = w4[i];
        float q0 = fminf(1.f, fmaxf(-1.f, rintf(v.x / denom)));
        float q1 = fminf(1.f, fmaxf(-1.f, rintf(v.y / denom)));
        float q2 = fminf(1.f, fmaxf(-1.f, rintf(v.z / denom)));
        float q3 = fminf(1.f, fmaxf(-1.f, rintf(v.w / denom)));
        cm += (q0 < -0.5f) + (q1 < -0.5f) + (q2 < -0.5f) + (q3 < -0.5f);
        cp += (q0 >  0.5f) + (q1 >  0.5f) + (q2 >  0.5f) + (q3 >  0.5f);
        if (do_store) {
            unsigned b0 = (q0 < -0.5f) ? 0xBF80u : (q0 > 0.5f ? 0x3F80u : 0u);
            unsigned b1 = (q1 < -0.5f) ? 0xBF80u : (q1 > 0.5f ? 0x3F80u : 0u);
            unsigned b2 = (q2 < -0.5f) ? 0xBF80u : (q2 > 0.5f ? 0x3F80u : 0u);
            unsigned b3 = (q3 < -0.5f) ? 0xBF80u : (q3 > 0.5f ? 0x3F80u : 0u);
            uint2 pk;
            pk.x = b0 | (b1 << 16);
            pk.y = b2 | (b3 << 16);
            ((uint2*)wq)[i] = pk;
        }
    }
    __shared__ unsigned smc[512];
    smc[threadIdx.x] = cm;
    smc[256 + threadIdx.x] = cp;
    __syncthreads();
    for (int s = 128; s > 0; s >>= 1) {
        if (threadIdx.x < s) {
            smc[threadIdx.x] += smc[threadIdx.x + s];
            smc[256 + threadIdx.x] += smc[256 + threadIdx.x + s];
        }
        __syncthreads();
    }
    if (threadIdx.x == 0) {
        atomicAdd(&counts[0], smc[0]);
        atomicAdd(&counts[1], smc[256]);
    }
}

// ---------------- entropy + t_current ----------------
__global__ void k_fin(const unsigned int* __restrict__ counts,
                      float* __restrict__ outs) {
    double n = NW;
    double c1 = (double)counts[0];
    double c2 = (double)counts[1];
    double c0 = n - c1 - c2;
    double H = 0.0;
    if (c1 > 0.0) { double p = c1 / n; H -= p * log2(p); }
    if (c0 > 0.0) { double p = c0 / n; H -= p * log2(p); }
    if (c2 > 0.0) { double p = c2 / n; H -= p * log2(p); }
    float Hf = (float)H;
    float heat = 100.0f * fmaxf(Hf, 0.0f);
    outs[0] = -10.0f + (50.0f + heat) * 0.5f;
    outs[1] = Hf;
}

// ===== R15: fat-wave 256x256 GEMM — 4 waves, per-wave 128x128 =====
// C[M,N] = A[M,K] * B[N,K]^T. 256 threads = 4 waves (2M x 2N).
// LDS 128KB: buf[2] x {A0,A1,B0,B1} slots (16KB = 128 rows x 64 K),
// fragment-major: frag (ks*8+sub16) at slot + frag*1024 + lane*16, holding
// row sub16*16+(lane&15), K ks*32+(lane>>4)*8. All ds_read_b128 contiguous.
//
// LDS-read traffic cut: per-wave 128x128 output -> per block per K-tile
// 128 b128 reads (vs 192 at 128x64/8-wave): 1536 vs 2304 cyc on the
// co-binding LDS pipe. MFMA unchanged (512/tile = 2483 cyc/CU).
//
// Schedule: ONE phase per K-tile: [32 ds_read][16 gload16 stage t+1 into
// OTHER buffer][128 MFMA][vmcnt(0) lgkmcnt(0)][BAR].
// Hazards: stages of t+1 target buf[(t+1)&1], freed because tile t-1's
// readers all lgkm-waited (compiler-inserted, before their MFMAs) before
// passing t-1's closing BAR. Reads of t+1 start only after t's closing
// BAR, whose preceding vmcnt(0) drains this tile's stages (cover ~2500cyc).
// Registers: acc 8x8 f32x4 = 256 (AGPR file) + 128 operand VGPR + addr.

#define SSLOT(PLO, PHI, D) do {                                   \
    gload16((PLO),      (D));                                     \
    gload16((PHI),      (char*)(D) + 4096);                       \
    gload16((PLO) + 32, (char*)(D) + 8192);                       \
    gload16((PHI) + 32, (char*)(D) + 12288);                      \
    (PLO) += 64; (PHI) += 64; } while (0)

__global__ __launch_bounds__(256, 1) void k_gemm3(const unsigned short* __restrict__ A,
                                                  const unsigned short* __restrict__ B,
                                                  float* __restrict__ C) {
    extern __shared__ char smem[];
    const int tid  = threadIdx.x;
    const int lane = tid & 63;
    const int wid  = tid >> 6;        // 0..3
    const int wr   = wid >> 1;        // 0..1 (M half)
    const int wc   = wid & 1;         // 0..1 (N half)
    const int fr   = lane & 15;
    const int khi  = lane >> 4;       // 0..3

    // R9 XCD/L2-locality mapping (bijective, 512 blocks)
    const int lin = blockIdx.x;
    const int x   = lin & 7;
    const int j   = lin >> 3;
    const int tm  = ((x & 1) << 4) + (j & 15);   // 0..31
    const int tn  = ((x >> 1) << 2) + (j >> 4);  // 0..15

    // staging source pointers: pass-lo rows (tid>>6)*16+(tid&15) in 0..63,
    // pass-hi +64 rows; col (tid>>4&3)*8; +32 elems for ks=1 passes.
    const int srow = ((tid >> 6) << 4) + (tid & 15);   // 0..63
    const int scol = ((tid >> 4) & 3) * 8;
    const unsigned short* pA0lo = A + (size_t)(tm * 256 +       srow) * K_DIM + scol;
    const unsigned short* pA0hi = pA0lo + (size_t)64 * K_DIM;
    const unsigned short* pA1lo = A + (size_t)(tm * 256 + 128 + srow) * K_DIM + scol;
    const unsigned short* pA1hi = pA1lo + (size_t)64 * K_DIM;
    const unsigned short* pB0lo = B + (size_t)(tn * 256 +       srow) * K_DIM + scol;
    const unsigned short* pB0hi = pB0lo + (size_t)64 * K_DIM;
    const unsigned short* pB1lo = B + (size_t)(tn * 256 + 128 + srow) * K_DIM + scol;
    const unsigned short* pB1hi = pB1lo + (size_t)64 * K_DIM;

    char* const dst = smem + tid * 16;
#define DL3(BUF, SLOT) (dst + ((BUF) << 16) + ((SLOT) << 14))

    f32x4 acc[8][8] = {};

    // prologue: stage T0 all 4 slots; drain; publish
    SSLOT(pA0lo, pA0hi, DL3(0, 0));
    SSLOT(pA1lo, pA1hi, DL3(0, 1));
    SSLOT(pB0lo, pB0hi, DL3(0, 2));
    SSLOT(pB1lo, pB1hi, DL3(0, 3));
    asm volatile("s_waitcnt vmcnt(0)" ::: "memory");
    __builtin_amdgcn_s_barrier();

    bf16x8 afr0[8], afr1[8], bfr0[8], bfr1[8];
    const char* abase = smem + ((size_t)wr << 14) + lane * 16;
    const char* bbase = smem + 32768 + ((size_t)wc << 14) + lane * 16;

    for (int t = 0; t < 64; ++t) {
        const char* ap = abase + ((size_t)(t & 1) << 16);
        const char* bp = bbase + ((size_t)(t & 1) << 16);
        const int nb = (t + 1) & 1;

        // reads: ks0 frags 0-7, ks1 frags 8-15 (A and B)
#pragma unroll
        for (int m = 0; m < 8; ++m) afr0[m] = *(const bf16x8*)(ap + m * 1024);
#pragma unroll
        for (int n = 0; n < 8; ++n) bfr0[n] = *(const bf16x8*)(bp + n * 1024);
#pragma unroll
        for (int m = 0; m < 8; ++m) afr1[m] = *(const bf16x8*)(ap + (8 + m) * 1024);
#pragma unroll
        for (int n = 0; n < 8; ++n) bfr1[n] = *(const bf16x8*)(bp + (8 + n) * 1024);

        // stage tile t+1 into the OTHER buffer
        if (t < 63) {
            SSLOT(pA0lo, pA0hi, DL3(nb, 0));
            SSLOT(pA1lo, pA1hi, DL3(nb, 1));
            SSLOT(pB0lo, pB0hi, DL3(nb, 2));
            SSLOT(pB1lo, pB1hi, DL3(nb, 3));
        }

        __builtin_amdgcn_s_setprio(1);
#pragma unroll
        for (int m = 0; m < 8; ++m)
#pragma unroll
            for (int n = 0; n < 8; ++n)
                acc[m][n] = __builtin_amdgcn_mfma_f32_16x16x32_bf16(afr0[m], bfr0[n], acc[m][n], 0, 0, 0);
#pragma unroll
        for (int m = 0; m < 8; ++m)
#pragma unroll
            for (int n = 0; n < 8; ++n)
                acc[m][n] = __builtin_amdgcn_mfma_f32_16x16x32_bf16(afr1[m], bfr1[n], acc[m][n], 0, 0, 0);
        __builtin_amdgcn_s_setprio(0);

        asm volatile("s_waitcnt vmcnt(0) lgkmcnt(0)" ::: "memory");
        __builtin_amdgcn_s_barrier();
    }

    // epilogue: C/D layout col = lane&15, row = khi*4 + j
    const size_t crow = (size_t)(tm * 256 + wr * 128 + khi * 4);
    const int    ccol = tn * 256 + wc * 128 + fr;
#pragma unroll
    for (int m = 0; m < 8; ++m)
#pragma unroll
        for (int n = 0; n < 8; ++n) {
            float* cp = C + (crow + m * 16) * N_OUT + (ccol + n * 16);
#pragma unroll
            for (int jj = 0; jj < 4; ++jj)
                cp[(size_t)jj * N_OUT] = acc[m][n][jj];
        }
#undef DL3
}

// ---------------- fallback fp32 GEMM (only if ws too small) ----------------
__global__ __launch_bounds__(256) void fb_gemm(const float* __restrict__ X,
                                               const float* __restrict__ W,
                                               const double* __restrict__ sum,
                                               float* __restrict__ C) {
    __shared__ float Xs[64][33];
    __shared__ float Ws[64][33];
    const float gamma = (float)(*sum / NW);
    const float denom = gamma + 1e-8f;
    const int tid = threadIdx.x;
    const int bm = blockIdx.y * 64;
    const int bn = blockIdx.x * 64;
    const int tr = tid >> 4, tc = tid & 15;
    const int lrow = tid >> 2;
    const int lcol = (tid & 3) * 8;
    float acc[4][4] = {};
    for (int k0 = 0; k0 < K_DIM; k0 += 32) {
        const float4* xs = (const float4*)(X + (size_t)(bm + lrow) * K_DIM + k0 + lcol);
        float4 v0 = xs[0], v1 = xs[1];
        Xs[lrow][lcol + 0] = v0.x; Xs[lrow][lcol + 1] = v0.y;
        Xs[lrow][lcol + 2] = v0.z; Xs[lrow][lcol + 3] = v0.w;
        Xs[lrow][lcol + 4] = v1.x; Xs[lrow][lcol + 5] = v1.y;
        Xs[lrow][lcol + 6] = v1.z; Xs[lrow][lcol + 7] = v1.w;
        const float4* wsrc = (const float4*)(W + (size_t)(bn + lrow) * K_DIM + k0 + lcol);
        float4 w0 = wsrc[0], w1 = wsrc[1];
        Ws[lrow][lcol + 0] = fminf(1.f, fmaxf(-1.f, rintf(w0.x / denom)));
        Ws[lrow][lcol + 1] = fminf(1.f, fmaxf(-1.f, rintf(w0.y / denom)));
        Ws[lrow][lcol + 2] = fminf(1.f, fmaxf(-1.f, rintf(w0.z / denom)));
        Ws[lrow][lcol + 3] = fminf(1.f, fmaxf(-1.f, rintf(w0.w / denom)));
        Ws[lrow][lcol + 4] = fminf(1.f, fmaxf(-1.f, rintf(w1.x / denom)));
        Ws[lrow][lcol + 5] = fminf(1.f, fmaxf(-1.f, rintf(w1.y / denom)));
        Ws[lrow][lcol + 6] = fminf(1.f, fmaxf(-1.f, rintf(w1.z / denom)));
        Ws[lrow][lcol + 7] = fminf(1.f, fmaxf(-1.f, rintf(w1.w / denom)));
        __syncthreads();
#pragma unroll 8
        for (int kk = 0; kk < 32; ++kk) {
            float a0 = Xs[tr * 4 + 0][kk], a1 = Xs[tr * 4 + 1][kk];
            float a2 = Xs[tr * 4 + 2][kk], a3 = Xs[tr * 4 + 3][kk];
            float b0 = Ws[tc * 4 + 0][kk], b1 = Ws[tc * 4 + 1][kk];
            float b2 = Ws[tc * 4 + 2][kk], b3 = Ws[tc * 4 + 3][kk];
            acc[0][0] += a0 * b0; acc[0][1] += a0 * b1; acc[0][2] += a0 * b2; acc[0][3] += a0 * b3;
            acc[1][0] += a1 * b0; acc[1][1] += a1 * b1; acc[1][2] += a1 * b2; acc[1][3] += a1 * b3;
            acc[2][0] += a2 * b0; acc[2][1] += a2 * b1; acc[2][2] += a2 * b2; acc[2][3] += a2 * b3;
            acc[3][0] += a3 * b0; acc[3][1] += a3 * b1; acc[3][2] += a3 * b2; acc[3][3] += a3 * b3;
        }
        __syncthreads();
    }
#pragma unroll
    for (int i = 0; i < 4; ++i)
#pragma unroll
        for (int jj = 0; jj < 4; ++jj)
            C[(size_t)(bm + tr * 4 + i) * N_OUT + (bn + tc * 4 + jj)] = acc[i][jj];
}

extern "C" void kernel_launch(void* const* d_in, const int* in_sizes, int n_in,
                              void* d_out, int out_size, void* d_ws, size_t ws_size,
                              hipStream_t stream) {
    (void)in_sizes; (void)n_in; (void)out_size;
    const float* x = (const float*)d_in[0];
    const float* w = (const float*)d_in[1];
    float* out = (float*)d_out;
    float* scalars = out + (size_t)M_ROWS * N_OUT;   // [t_current, entropy]

    double* sum = (double*)d_ws;
    unsigned int* counts = (unsigned int*)((char*)d_ws + 8);
    unsigned short* xb = (unsigned short*)((char*)d_ws + 64);
    unsigned short* wq = (unsigned short*)((char*)d_ws + 64 + (size_t)M_ROWS * K_DIM * 2);

    const size_t need = 64 + (size_t)M_ROWS * K_DIM * 2 + (size_t)N_OUT * K_DIM * 2;
    const int fast = (ws_size >= need);

    hipMemsetAsync(d_ws, 0, 32, stream);

    if (fast) {
        k_gamma_cvt<<<2048, 256, 0, stream>>>(w, x, xb, sum);
        k_quant<<<1024, 256, 0, stream>>>(w, sum, wq, counts, 1);
        k_fin<<<1, 1, 0, stream>>>(counts, scalars);
        hipFuncSetAttribute(reinterpret_cast<const void*>(k_gemm3),
                            hipFuncAttributeMaxDynamicSharedMemorySize, 131072);
        k_gemm3<<<dim3(512), 256, 131072, stream>>>(xb, wq, out);
    } else {
        k_gamma<<<1024, 256, 0, stream>>>(w, sum);
        k_quant<<<1024, 256, 0, stream>>>(w, sum, nullptr, counts, 0);
        k_fin<<<1, 1, 0, stream>>>(counts, scalars);
        dim3 grid(N_OUT / 64, M_ROWS / 64);
        fb_gemm<<<grid, 256, 0, stream>>>(x, w, sum, out);
    }
}

// Round 16
// 367.697 us; speedup vs baseline: 1.1718x; 1.1718x over previous
//
#include <hip/hip_runtime.h>
#include <stdint.h>

typedef short bf16x8 __attribute__((ext_vector_type(8)));
typedef float f32x4 __attribute__((ext_vector_type(4)));

#define M_ROWS 8192
#define N_OUT  4096
#define K_DIM  4096
#define NW     16777216.0   // number of weights

// ---------------- async global->LDS (16B per lane) ----------------
__device__ __forceinline__ void gload16(const void* g, void* l) {
    __builtin_amdgcn_global_load_lds((const __attribute__((address_space(1))) void*)g,
                                     (__attribute__((address_space(3))) void*)l,
                                     16, 0, 0);
}

// RNE f32 -> bf16 bits
__device__ __forceinline__ unsigned short f2bf(float f) {
    unsigned u = __float_as_uint(f);
    unsigned r = 0x7FFFu + ((u >> 16) & 1u);
    return (unsigned short)((u + r) >> 16);
}

// ------- fused: gamma partial-sum (W) + x f32->bf16 conversion -------
__global__ __launch_bounds__(256) void k_gamma_cvt(const float* __restrict__ w,
                                                   const float* __restrict__ x,
                                                   unsigned short* __restrict__ xb,
                                                   double* __restrict__ sum) {
    const int idx = blockIdx.x * blockDim.x + threadIdx.x;
    const int stride = gridDim.x * blockDim.x;

    const int wn4 = (K_DIM * N_OUT) / 4;
    const float4* w4 = (const float4*)w;
    double local = 0.0;
    for (int i = idx; i < wn4; i += stride) {
        float4 v = w4[i];
        local += (double)fabsf(v.x) + (double)fabsf(v.y) +
                 (double)fabsf(v.z) + (double)fabsf(v.w);
    }

    const int xn4 = (M_ROWS * K_DIM) / 4;
    const float4* x4 = (const float4*)x;
    for (int i = idx; i < xn4; i += stride) {
        float4 v = x4[i];
        uint2 pk;
        pk.x = (unsigned)f2bf(v.x) | ((unsigned)f2bf(v.y) << 16);
        pk.y = (unsigned)f2bf(v.z) | ((unsigned)f2bf(v.w) << 16);
        ((uint2*)xb)[i] = pk;
    }

    __shared__ double sm[256];
    sm[threadIdx.x] = local;
    __syncthreads();
    for (int s = 128; s > 0; s >>= 1) {
        if (threadIdx.x < s) sm[threadIdx.x] += sm[threadIdx.x + s];
        __syncthreads();
    }
    if (threadIdx.x == 0) atomicAdd(sum, sm[0]);
}

// ---------------- gamma only (fallback path) ----------------
__global__ __launch_bounds__(256) void k_gamma(const float* __restrict__ w,
                                               double* __restrict__ sum) {
    const int n4 = (K_DIM * N_OUT) / 4;
    int idx = blockIdx.x * blockDim.x + threadIdx.x;
    int stride = gridDim.x * blockDim.x;
    const float4* w4 = (const float4*)w;
    double local = 0.0;
    for (int i = idx; i < n4; i += stride) {
        float4 v = w4[i];
        local += (double)fabsf(v.x) + (double)fabsf(v.y) +
                 (double)fabsf(v.z) + (double)fabsf(v.w);
    }
    __shared__ double sm[256];
    sm[threadIdx.x] = local;
    __syncthreads();
    for (int s = 128; s > 0; s >>= 1) {
        if (threadIdx.x < s) sm[threadIdx.x] += sm[threadIdx.x + s];
        __syncthreads();
    }
    if (threadIdx.x == 0) atomicAdd(sum, sm[0]);
}

// ---------------- quantize W -> ternary bf16 + bin counts ----------------
__global__ __launch_bounds__(256) void k_quant(const float* __restrict__ w,
                                               const double* __restrict__ sum,
                                               unsigned short* __restrict__ wq,
                                               unsigned int* __restrict__ counts,
                                               int do_store) {
    const float gamma = (float)(*sum / NW);
    const float denom = gamma + 1e-8f;
    const int n4 = (K_DIM * N_OUT) / 4;
    int idx = blockIdx.x * blockDim.x + threadIdx.x;
    int stride = gridDim.x * blockDim.x;
    const float4* w4 = (const float4*)w;
    unsigned cm = 0, cp = 0;
    for (int i = idx; i < n4; i += stride) {
        float4 v = w4[i];
        float q0 = fminf(1.f, fmaxf(-1.f, rintf(v.x / denom)));
        float q1 = fminf(1.f, fmaxf(-1.f, rintf(v.y / denom)));
        float q2 = fminf(1.f, fmaxf(-1.f, rintf(v.z / denom)));
        float q3 = fminf(1.f, fmaxf(-1.f, rintf(v.w / denom)));
        cm += (q0 < -0.5f) + (q1 < -0.5f) + (q2 < -0.5f) + (q3 < -0.5f);
        cp += (q0 >  0.5f) + (q1 >  0.5f) + (q2 >  0.5f) + (q3 >  0.5f);
        if (do_store) {
            unsigned b0 = (q0 < -0.5f) ? 0xBF80u : (q0 > 0.5f ? 0x3F80u : 0u);
            unsigned b1 = (q1 < -0.5f) ? 0xBF80u : (q1 > 0.5f ? 0x3F80u : 0u);
            unsigned b2 = (q2 < -0.5f) ? 0xBF80u : (q2 > 0.5f ? 0x3F80u : 0u);
            unsigned b3 = (q3 < -0.5f) ? 0xBF80u : (q3 > 0.5f ? 0x3F80u : 0u);
            uint2 pk;
            pk.x = b0 | (b1 << 16);
            pk.y = b2 | (b3 << 16);
            ((uint2*)wq)[i] = pk;
        }
    }
    __shared__ unsigned smc[512];
    smc[threadIdx.x] = cm;
    smc[256 + threadIdx.x] = cp;
    __syncthreads();
    for (int s = 128; s > 0; s >>= 1) {
        if (threadIdx.x < s) {
            smc[threadIdx.x] += smc[threadIdx.x + s];
            smc[256 + threadIdx.x] += smc[256 + threadIdx.x + s];
        }
        __syncthreads();
    }
    if (threadIdx.x == 0) {
        atomicAdd(&counts[0], smc[0]);
        atomicAdd(&counts[1], smc[256]);
    }
}

// ---------------- entropy + t_current ----------------
__global__ void k_fin(const unsigned int* __restrict__ counts,
                      float* __restrict__ outs) {
    double n = NW;
    double c1 = (double)counts[0];
    double c2 = (double)counts[1];
    double c0 = n - c1 - c2;
    double H = 0.0;
    if (c1 > 0.0) { double p = c1 / n; H -= p * log2(p); }
    if (c0 > 0.0) { double p = c0 / n; H -= p * log2(p); }
    if (c2 > 0.0) { double p = c2 / n; H -= p * log2(p); }
    float Hf = (float)H;
    float heat = 100.0f * fmaxf(Hf, 0.0f);
    outs[0] = -10.0f + (50.0f + heat) * 0.5f;
    outs[1] = Hf;
}

// ===== 256x256 bf16 MFMA GEMM, 8-phase / 2-Ktile iter (R12 body, FINAL) =====
// Session-best verified configuration (reproduced twice: 367.5 / 368.7 us).
// GEMM 288us ~ 955 TF (38% dense peak), MfmaUtil ~41%, 0 bank conflicts,
// FETCH ~380MB. Measured pipe totals per CU per iter: LDS 5632 cyc +
// MFMA 4966 cyc, wall ~10800 cyc (serialized): the plain-HIP structure
// ceiling for this body — 8 schedule variants, 3 LDS layouts, 3 XCD maps,
// and a fat-wave tile all measured neutral-or-worse.

#define MFMA_Q(ACCM, ACCN, AF, BF)                                             \
    __builtin_amdgcn_s_setprio(1);                                             \
    _Pragma("unroll") for (int mm = 0; mm < 4; ++mm)                           \
    _Pragma("unroll") for (int nn = 0; nn < 2; ++nn)                           \
    _Pragma("unroll") for (int ks = 0; ks < 2; ++ks)                           \
        acc[(ACCM) + mm][(ACCN) + nn] = __builtin_amdgcn_mfma_f32_16x16x32_bf16( \
            AF[mm][ks], BF[nn][ks], acc[(ACCM) + mm][(ACCN) + nn], 0, 0, 0);   \
    __builtin_amdgcn_s_setprio(0);

#define RD_A(PTR, BASE)                                                        \
    _Pragma("unroll") for (int mm = 0; mm < 4; ++mm)                           \
    _Pragma("unroll") for (int ks = 0; ks < 2; ++ks)                           \
        afr[mm][ks] = *(const bf16x8*)((PTR) + (ks * 8 + (BASE) + mm) * 1024);

#define RD_B(PTR, BASE, DST)                                                   \
    _Pragma("unroll") for (int nn = 0; nn < 2; ++nn)                           \
    _Pragma("unroll") for (int ks = 0; ks < 2; ++ks)                           \
        DST[nn][ks] = *(const bf16x8*)((PTR) + (ks * 8 + (BASE) + nn) * 1024);

#define BAR   __builtin_amdgcn_s_barrier()
#define LGKM0 asm volatile("s_waitcnt lgkmcnt(0)" ::: "memory")

#define STAGE2(P, D)  do { gload16((P), (D)); gload16((P) + 32, (char*)(D) + 8192); (P) += 64; } while (0)

__global__ __launch_bounds__(512, 2) void k_gemm2(const unsigned short* __restrict__ A,
                                                  const unsigned short* __restrict__ B,
                                                  float* __restrict__ C) {
    extern __shared__ char smem[];
    const int tid  = threadIdx.x;
    const int lane = tid & 63;
    const int wid  = tid >> 6;
    const int wr   = wid >> 2;        // 0..1  (M)
    const int wc   = wid & 3;         // 0..3  (N)
    const int fr   = lane & 15;
    const int khi  = lane >> 4;       // 0..3

    // R9 XCD/L2-locality mapping (bijective)
    const int lin = blockIdx.x;
    const int x   = lin & 7;
    const int j   = lin >> 3;
    const int tm  = ((x & 1) << 4) + (j & 15);   // 0..31
    const int tn  = ((x >> 1) << 2) + (j >> 4);  // 0..15

    // hoisted per-thread staging pointers (one per LDS slot)
    const int srow = ((tid >> 6) << 4) + (tid & 15);   // 0..127
    const int scol = ((tid >> 4) & 3) * 8;             // 0,8,16,24
    const unsigned short* pA0 = A + (size_t)(tm * 256 +       srow) * K_DIM + scol;
    const unsigned short* pA1 = A + (size_t)(tm * 256 + 128 + srow) * K_DIM + scol;
    const unsigned short* pB0 = B + (size_t)(tn * 256 +       srow) * K_DIM + scol;
    const unsigned short* pB1 = B + (size_t)(tn * 256 + 128 + srow) * K_DIM + scol;

    char* const dst = smem + tid * 16;
#define DL(BUF, SLOT) (dst + ((BUF) << 16) + ((SLOT) << 14))

    f32x4 acc[8][4] = {};

    // prologue: T0.{A0,A1,B0,B1} + T1.{B0,B1}; counted gate; publish
    STAGE2(pA0, DL(0, 0));
    STAGE2(pA1, DL(0, 1));
    STAGE2(pB0, DL(0, 2));
    STAGE2(pB1, DL(0, 3));
    STAGE2(pB0, DL(1, 2));
    STAGE2(pB1, DL(1, 3));
    asm volatile("s_waitcnt vmcnt(4)" ::: "memory");
    BAR;

    bf16x8 afr[4][2], b0[2][2], b1[2][2];
    const int bsel = (wc & 1) * 4;

    const char* aE = smem + ((size_t)wr << 14) + lane * 16;
    const char* bE = smem + 32768 + ((size_t)(wc >> 1) << 14) + bsel * 1024 + lane * 16;
    const char* aO = aE + 65536;
    const char* bO = bE + 65536;

    for (int it = 0; it < 32; ++it) {
        const bool more = (it < 31);

        // ---- ph0: reads E:A(rows0-63)+B(n0) [12]; stage T(o).A0
        RD_A(aE, 0)
        RD_B(bE, 0, b0)
        STAGE2(pA0, DL(1, 0));
        BAR; LGKM0;
        MFMA_Q(0, 0, afr, b0)
        BAR;

        // ---- ph1: reads E:B(n1) [4]; stage T(o).A1
        RD_B(bE, 2, b1)
        STAGE2(pA1, DL(1, 1));
        BAR; LGKM0;
        MFMA_Q(0, 2, afr, b1)
        BAR;

        // ---- ph2: reads E:A(rows64-127) [8]; stage T(e+2).B0
        RD_A(aE, 4)
        if (more) STAGE2(pB0, DL(0, 2));
        BAR; LGKM0;
        MFMA_Q(4, 2, afr, b1)
        BAR;

        // ---- ph3: no reads; stage T(e+2).B1; MFMA; GATE
        if (more) STAGE2(pB1, DL(0, 3));
        BAR; LGKM0;
        MFMA_Q(4, 0, afr, b0)
        if (more) { asm volatile("s_waitcnt vmcnt(4)" ::: "memory"); }
        else      { asm volatile("s_waitcnt vmcnt(0)" ::: "memory"); }
        BAR;

        // ---- ph4: reads O:A(rows0-63)+B(n0) [12]; stage T(e+2).A0
        RD_A(aO, 0)
        RD_B(bO, 0, b0)
        if (more) STAGE2(pA0, DL(0, 0));
        BAR; LGKM0;
        MFMA_Q(0, 0, afr, b0)
        BAR;

        // ---- ph5: reads O:B(n1) [4]; stage T(e+2).A1
        RD_B(bO, 2, b1)
        if (more) STAGE2(pA1, DL(0, 1));
        BAR; LGKM0;
        MFMA_Q(0, 2, afr, b1)
        BAR;

        // ---- ph6: reads O:A(rows64-127) [8]; stage T(o+2).B0
        RD_A(aO, 4)
        if (more) STAGE2(pB0, DL(1, 2));
        BAR; LGKM0;
        MFMA_Q(4, 2, afr, b1)
        BAR;

        // ---- ph7: no reads; stage T(o+2).B1; MFMA; GATE
        if (more) STAGE2(pB1, DL(1, 3));
        BAR; LGKM0;
        MFMA_Q(4, 0, afr, b0)
        if (more) { asm volatile("s_waitcnt vmcnt(4)" ::: "memory"); }
        else      { asm volatile("s_waitcnt vmcnt(0)" ::: "memory"); }
        BAR;
    }
    asm volatile("s_waitcnt vmcnt(0)" ::: "memory");

    // epilogue: C/D layout col = lane&15, row = khi*4 + j
    const size_t crow = (size_t)(tm * 256 + wr * 128 + khi * 4);
    const int    ccol = tn * 256 + wc * 64 + fr;
#pragma unroll
    for (int m = 0; m < 8; ++m)
#pragma unroll
        for (int n = 0; n < 4; ++n) {
            float* cp = C + (crow + m * 16) * N_OUT + (ccol + n * 16);
#pragma unroll
            for (int jj = 0; jj < 4; ++jj)
                cp[(size_t)jj * N_OUT] = acc[m][n][jj];
        }
#undef DL
}

// ---------------- fallback fp32 GEMM (only if ws too small) ----------------
__global__ __launch_bounds__(256) void fb_gemm(const float* __restrict__ X,
                                               const float* __restrict__ W,
                                               const double* __restrict__ sum,
                                               float* __restrict__ C) {
    __shared__ float Xs[64][33];
    __shared__ float Ws[64][33];
    const float gamma = (float)(*sum / NW);
    const float denom = gamma + 1e-8f;
    const int tid = threadIdx.x;
    const int bm = blockIdx.y * 64;
    const int bn = blockIdx.x * 64;
    const int tr = tid >> 4, tc = tid & 15;
    const int lrow = tid >> 2;
    const int lcol = (tid & 3) * 8;
    float acc[4][4] = {};
    for (int k0 = 0; k0 < K_DIM; k0 += 32) {
        const float4* xs = (const float4*)(X + (size_t)(bm + lrow) * K_DIM + k0 + lcol);
        float4 v0 = xs[0], v1 = xs[1];
        Xs[lrow][lcol + 0] = v0.x; Xs[lrow][lcol + 1] = v0.y;
        Xs[lrow][lcol + 2] = v0.z; Xs[lrow][lcol + 3] = v0.w;
        Xs[lrow][lcol + 4] = v1.x; Xs[lrow][lcol + 5] = v1.y;
        Xs[lrow][lcol + 6] = v1.z; Xs[lrow][lcol + 7] = v1.w;
        const float4* wsrc = (const float4*)(W + (size_t)(bn + lrow) * K_DIM + k0 + lcol);
        float4 w0 = wsrc[0], w1 = wsrc[1];
        Ws[lrow][lcol + 0] = fminf(1.f, fmaxf(-1.f, rintf(w0.x / denom)));
        Ws[lrow][lcol + 1] = fminf(1.f, fmaxf(-1.f, rintf(w0.y / denom)));
        Ws[lrow][lcol + 2] = fminf(1.f, fmaxf(-1.f, rintf(w0.z / denom)));
        Ws[lrow][lcol + 3] = fminf(1.f, fmaxf(-1.f, rintf(w0.w / denom)));
        Ws[lrow][lcol + 4] = fminf(1.f, fmaxf(-1.f, rintf(w1.x / denom)));
        Ws[lrow][lcol + 5] = fminf(1.f, fmaxf(-1.f, rintf(w1.y / denom)));
        Ws[lrow][lcol + 6] = fminf(1.f, fmaxf(-1.f, rintf(w1.z / denom)));
        Ws[lrow][lcol + 7] = fminf(1.f, fmaxf(-1.f, rintf(w1.w / denom)));
        __syncthreads();
#pragma unroll 8
        for (int kk = 0; kk < 32; ++kk) {
            float a0 = Xs[tr * 4 + 0][kk], a1 = Xs[tr * 4 + 1][kk];
            float a2 = Xs[tr * 4 + 2][kk], a3 = Xs[tr * 4 + 3][kk];
            float b0 = Ws[tc * 4 + 0][kk], b1 = Ws[tc * 4 + 1][kk];
            float b2 = Ws[tc * 4 + 2][kk], b3 = Ws[tc * 4 + 3][kk];
            acc[0][0] += a0 * b0; acc[0][1] += a0 * b1; acc[0][2] += a0 * b2; acc[0][3] += a0 * b3;
            acc[1][0] += a1 * b0; acc[1][1] += a1 * b1; acc[1][2] += a1 * b2; acc[1][3] += a1 * b3;
            acc[2][0] += a2 * b0; acc[2][1] += a2 * b1; acc[2][2] += a2 * b2; acc[2][3] += a2 * b3;
            acc[3][0] += a3 * b0; acc[3][1] += a3 * b1; acc[3][2] += a3 * b2; acc[3][3] += a3 * b3;
        }
        __syncthreads();
    }
#pragma unroll
    for (int i = 0; i < 4; ++i)
#pragma unroll
        for (int jj = 0; jj < 4; ++jj)
            C[(size_t)(bm + tr * 4 + i) * N_OUT + (bn + tc * 4 + jj)] = acc[i][jj];
}

extern "C" void kernel_launch(void* const* d_in, const int* in_sizes, int n_in,
                              void* d_out, int out_size, void* d_ws, size_t ws_size,
                              hipStream_t stream) {
    (void)in_sizes; (void)n_in; (void)out_size;
    const float* x = (const float*)d_in[0];
    const float* w = (const float*)d_in[1];
    float* out = (float*)d_out;
    float* scalars = out + (size_t)M_ROWS * N_OUT;   // [t_current, entropy]

    double* sum = (double*)d_ws;
    unsigned int* counts = (unsigned int*)((char*)d_ws + 8);
    unsigned short* xb = (unsigned short*)((char*)d_ws + 64);
    unsigned short* wq = (unsigned short*)((char*)d_ws + 64 + (size_t)M_ROWS * K_DIM * 2);

    const size_t need = 64 + (size_t)M_ROWS * K_DIM * 2 + (size_t)N_OUT * K_DIM * 2;
    const int fast = (ws_size >= need);

    hipMemsetAsync(d_ws, 0, 32, stream);

    if (fast) {
        k_gamma_cvt<<<2048, 256, 0, stream>>>(w, x, xb, sum);
        k_quant<<<1024, 256, 0, stream>>>(w, sum, wq, counts, 1);
        k_fin<<<1, 1, 0, stream>>>(counts, scalars);
        hipFuncSetAttribute(reinterpret_cast<const void*>(k_gemm2),
                            hipFuncAttributeMaxDynamicSharedMemorySize, 131072);
        k_gemm2<<<dim3(512), 512, 131072, stream>>>(xb, wq, out);
    } else {
        k_gamma<<<1024, 256, 0, stream>>>(w, sum);
        k_quant<<<1024, 256, 0, stream>>>(w, sum, nullptr, counts, 0);
        k_fin<<<1, 1, 0, stream>>>(counts, scalars);
        dim3 grid(N_OUT / 64, M_ROWS / 64);
        fb_gemm<<<grid, 256, 0, stream>>>(x, w, sum, out);
    }
}